// Round 4
// baseline (49.239 us; speedup 1.0000x reference)
//
#include <hip/hip_runtime.h>

#define SEQ 256
#define NENV 64
#define NGROUPS 12
#define GDIM 128
#define ROWS (SEQ * NENV)           // 16384
#define WPB 4                       // waves per block -> 256 threads
#define NBLOCKS (ROWS / WPB)        // 4096

// Fused kernel: per-block prologue computes v = Wg @ Wa[128:256] (L2-resident
// after the first blocks), then each wave processes one (s,e) row exactly as
// the measured-fastest R1 inner loop.
__global__ __launch_bounds__(WPB * 64)
void group_attn_fused(const float* __restrict__ ge,     // (ROWS, 12, 128)
                      const float* __restrict__ Wg,     // (128, 128)
                      const float* __restrict__ Wa,     // (256, 1)
                      float* __restrict__ out_weighted, // (ROWS, 128)
                      float* __restrict__ out_weights)  // (ROWS, 12)
{
    __shared__ float part[2][128];

    const int tid  = threadIdx.x;
    const int wave = tid >> 6;
    const int lane = tid & 63;
    const int row  = blockIdx.x * WPB + wave;

    // ---- Phase 0: v[d] = sum_a Wg[d][a] * Wa[128+a], split over 2 threads/dim.
    {
        const int d = tid & 127;
        const int h = tid >> 7;     // half of the K dim
        const float4* r4  = reinterpret_cast<const float4*>(Wg + d * 128 + h * 64);
        const float4* wa4 = reinterpret_cast<const float4*>(Wa + 128 + h * 64);
        float acc = 0.0f;
#pragma unroll
        for (int a = 0; a < 16; ++a) {
            const float4 r = r4[a];
            const float4 w = wa4[a];    // uniform address -> scalar loads
            acc += r.x * w.x + r.y * w.y + r.z * w.z + r.w * w.w;
        }
        part[h][d] = acc;
    }
    __syncthreads();

    // ---- Phase 1: one row per wave (R1 structure, measured fastest).
    const int half = lane >> 5;     // 0: even groups, 1: odd groups
    const int l32  = lane & 31;     // dims [l32*4, l32*4+3]

    // v fragment for my 4 dims (combine the two K-halves from LDS).
    float4 vf;
    {
        const float4 p0 = *reinterpret_cast<const float4*>(&part[0][l32 * 4]);
        const float4 p1 = *reinterpret_cast<const float4*>(&part[1][l32 * 4]);
        vf.x = p0.x + p1.x; vf.y = p0.y + p1.y;
        vf.z = p0.z + p1.z; vf.w = p0.w + p1.w;
    }

    const float* base = ge + (size_t)row * (NGROUPS * GDIM);

    // Load the whole 12x128 row: 6 steps x 64 lanes x float4.
    // Step t covers groups {2t (lanes 0..31), 2t+1 (lanes 32..63)}.
    float4 g[6];
    float  pdot[6];
#pragma unroll
    for (int t = 0; t < 6; ++t) {
        g[t] = *reinterpret_cast<const float4*>(base + t * 256 + lane * 4);
        pdot[t] = g[t].x * vf.x + g[t].y * vf.y + g[t].z * vf.z + g[t].w * vf.w;
    }

    // Reduce dots: 5-step butterfly within each half, then cross-half exchange
    // so every lane holds all 12 scores.
    float sc[12];
#pragma unroll
    for (int t = 0; t < 6; ++t) {
        float p = pdot[t];
        p += __shfl_xor(p, 1);
        p += __shfl_xor(p, 2);
        p += __shfl_xor(p, 4);
        p += __shfl_xor(p, 8);
        p += __shfl_xor(p, 16);
        float q = __shfl_xor(p, 32);
        sc[2 * t]     = half ? q : p;
        sc[2 * t + 1] = half ? p : q;
    }

    // Softmax over 12 scores (redundant in every lane).
    float m = sc[0];
#pragma unroll
    for (int i = 1; i < NGROUPS; ++i) m = fmaxf(m, sc[i]);
    float w[12];
    float sum = 0.0f;
#pragma unroll
    for (int i = 0; i < NGROUPS; ++i) {
        w[i] = __expf(sc[i] - m);
        sum += w[i];
    }
    const float inv = 1.0f / sum;
#pragma unroll
    for (int i = 0; i < NGROUPS; ++i) w[i] *= inv;

    // Weighted sum of group embeddings (data already in registers).
    float4 acc = make_float4(0.f, 0.f, 0.f, 0.f);
#pragma unroll
    for (int t = 0; t < 6; ++t) {
        const float wt = w[2 * t + half];
        acc.x += wt * g[t].x;
        acc.y += wt * g[t].y;
        acc.z += wt * g[t].z;
        acc.w += wt * g[t].w;
    }
    // Combine even-group half with odd-group half (same dims in lane^32).
    acc.x += __shfl_xor(acc.x, 32);
    acc.y += __shfl_xor(acc.y, 32);
    acc.z += __shfl_xor(acc.z, 32);
    acc.w += __shfl_xor(acc.w, 32);

    if (lane < 32) {
        *reinterpret_cast<float4*>(out_weighted + (size_t)row * GDIM + l32 * 4) = acc;
    } else if (lane < 32 + NGROUPS) {
        out_weights[(size_t)row * NGROUPS + (lane - 32)] = w[lane - 32];
    }
}

extern "C" void kernel_launch(void* const* d_in, const int* in_sizes, int n_in,
                              void* d_out, int out_size, void* d_ws, size_t ws_size,
                              hipStream_t stream) {
    // Inputs: 0 robot_states (unused) 1 group_embeddings 2 Wr (unused)
    // 3 br (unused) 4 Wg 5 bg (unused) 6 Wa 7 ba (unused)
    const float* ge = (const float*)d_in[1];
    const float* Wg = (const float*)d_in[4];
    const float* Wa = (const float*)d_in[6];

    float* out_weighted = (float*)d_out;                       // ROWS*128
    float* out_weights  = out_weighted + (size_t)ROWS * GDIM;  // ROWS*12

    group_attn_fused<<<NBLOCKS, WPB * 64, 0, stream>>>(
        ge, Wg, Wa, out_weighted, out_weights);
}

// Round 5
// 27.740 us; speedup vs baseline: 1.7751x; 1.7751x over previous
//
#include <hip/hip_runtime.h>

#define SEQ 256
#define NENV 64
#define NGROUPS 12
#define GDIM 128
#define ROWS (SEQ * NENV)           // 16384
#define WPB 4                       // waves per block -> 256 threads
#define NBLOCKS (ROWS / WPB)        // 4096

// Kernel 1: latency-minimal fold. Block d computes
//   v[d] = sum_a Wg[d][a] * Wa[128+a]
// One 64-lane wave per output dim: lane i loads Wg[d][2i..2i+1] (512B
// contiguous per block, whole 64KB issued in parallel across 128 blocks),
// 6-step butterfly reduce, lane 0 stores.
__global__ __launch_bounds__(64)
void fold_v(const float* __restrict__ Wg,
            const float* __restrict__ Wa,
            float* __restrict__ v) {
    const int d    = blockIdx.x;
    const int lane = threadIdx.x;
    const float2 r = *reinterpret_cast<const float2*>(Wg + d * 128 + 2 * lane);
    const float2 w = *reinterpret_cast<const float2*>(Wa + 128 + 2 * lane);
    float p = r.x * w.x + r.y * w.y;
    p += __shfl_xor(p, 1);
    p += __shfl_xor(p, 2);
    p += __shfl_xor(p, 4);
    p += __shfl_xor(p, 8);
    p += __shfl_xor(p, 16);
    p += __shfl_xor(p, 32);
    if (lane == 0) v[d] = p;
}

// Kernel 2: one 64-lane wave per (s,e) row — byte-identical to R1 (the
// measured-fastest structure: 27.9us total).
__global__ __launch_bounds__(WPB * 64)
void group_attn(const float* __restrict__ ge,     // (ROWS, 12, 128)
                const float* __restrict__ v,      // (128)
                float* __restrict__ out_weighted, // (ROWS, 128)
                float* __restrict__ out_weights)  // (ROWS, 12)
{
    const int wave = threadIdx.x >> 6;
    const int lane = threadIdx.x & 63;
    const int row  = blockIdx.x * WPB + wave;

    const int half = lane >> 5;     // 0: even groups, 1: odd groups
    const int l32  = lane & 31;     // dims [l32*4, l32*4+3]

    const float* base = ge + (size_t)row * (NGROUPS * GDIM);

    // v fragment for my 4 dims (L2-resident broadcast)
    const float4 vf = *reinterpret_cast<const float4*>(v + l32 * 4);

    // Load the whole 12x128 row: 6 steps x 64 lanes x float4.
    // Step t covers groups {2t (lanes 0..31), 2t+1 (lanes 32..63)}.
    float4 g[6];
    float  pdot[6];
#pragma unroll
    for (int t = 0; t < 6; ++t) {
        g[t] = *reinterpret_cast<const float4*>(base + t * 256 + lane * 4);
        pdot[t] = g[t].x * vf.x + g[t].y * vf.y + g[t].z * vf.z + g[t].w * vf.w;
    }

    // Reduce dots: 5-step butterfly within each half, then one cross-half
    // exchange so every lane holds all 12 scores.
    float sc[12];
#pragma unroll
    for (int t = 0; t < 6; ++t) {
        float p = pdot[t];
        p += __shfl_xor(p, 1);
        p += __shfl_xor(p, 2);
        p += __shfl_xor(p, 4);
        p += __shfl_xor(p, 8);
        p += __shfl_xor(p, 16);
        float q = __shfl_xor(p, 32);
        sc[2 * t]     = half ? q : p;
        sc[2 * t + 1] = half ? p : q;
    }

    // Softmax over 12 scores (redundant in every lane).
    float m = sc[0];
#pragma unroll
    for (int i = 1; i < NGROUPS; ++i) m = fmaxf(m, sc[i]);
    float w[12];
    float sum = 0.0f;
#pragma unroll
    for (int i = 0; i < NGROUPS; ++i) {
        w[i] = __expf(sc[i] - m);
        sum += w[i];
    }
    const float inv = 1.0f / sum;
#pragma unroll
    for (int i = 0; i < NGROUPS; ++i) w[i] *= inv;

    // Weighted sum of group embeddings (data already in registers).
    float4 acc = make_float4(0.f, 0.f, 0.f, 0.f);
#pragma unroll
    for (int t = 0; t < 6; ++t) {
        const float wt = w[2 * t + half];
        acc.x += wt * g[t].x;
        acc.y += wt * g[t].y;
        acc.z += wt * g[t].z;
        acc.w += wt * g[t].w;
    }
    // Combine even-group half with odd-group half (same dims in lane^32).
    acc.x += __shfl_xor(acc.x, 32);
    acc.y += __shfl_xor(acc.y, 32);
    acc.z += __shfl_xor(acc.z, 32);
    acc.w += __shfl_xor(acc.w, 32);

    if (lane < 32) {
        *reinterpret_cast<float4*>(out_weighted + (size_t)row * GDIM + l32 * 4) = acc;
    } else if (lane < 32 + NGROUPS) {
        out_weights[(size_t)row * NGROUPS + (lane - 32)] = w[lane - 32];
    }
}

extern "C" void kernel_launch(void* const* d_in, const int* in_sizes, int n_in,
                              void* d_out, int out_size, void* d_ws, size_t ws_size,
                              hipStream_t stream) {
    // Inputs: 0 robot_states (unused) 1 group_embeddings 2 Wr (unused)
    // 3 br (unused) 4 Wg 5 bg (unused) 6 Wa 7 ba (unused)
    const float* ge = (const float*)d_in[1];
    const float* Wg = (const float*)d_in[4];
    const float* Wa = (const float*)d_in[6];

    float* v = (float*)d_ws;                                   // 128 floats
    float* out_weighted = (float*)d_out;                       // ROWS*128
    float* out_weights  = out_weighted + (size_t)ROWS * GDIM;  // ROWS*12

    fold_v<<<GDIM, 64, 0, stream>>>(Wg, Wa, v);
    group_attn<<<NBLOCKS, WPB * 64, 0, stream>>>(
        ge, v, out_weighted, out_weights);
}